// Round 1
// baseline (122.888 us; speedup 1.0000x reference)
//
#include <hip/hip_runtime.h>
#include <math.h>

#define Bn 32
#define Ln 524288
#define NF 4
#define CHUNK 512
#define NBLK (Ln / CHUNK)      // 1024 blocks per batch row
#define BPL 16                 // blocks per lane in phase-2 scan
#define P2LANES (NBLK / BPL)   // 64 lanes

// ws layout in floats
#define COEF_OFF 0                       // 20 floats: per filter b0,b1,b2,a1,a2
#define M_OFF    64                      // 64 floats: M = A^CHUNK
#define M16_OFF  128                     // 64 floats: M^BPL
#define D_OFF    192                     // B*NBLK*8: zero-state block end states
#define S_OFF    (D_OFF + Bn * NBLK * 8) // B*NBLK*8: block entry states

// ---------------------------------------------------------------------------
// Kernel 0: coefficients (double), M = A^CHUNK via unit-state simulation,
// M16 = M^16 via repeated squaring. One block, 64 threads.
// ---------------------------------------------------------------------------
__global__ void precompute_k(const float* __restrict__ lr,
                             const float* __restrict__ ra,
                             const float* __restrict__ b0,
                             const float* __restrict__ b1,
                             const float* __restrict__ b2,
                             float* __restrict__ ws) {
    __shared__ double Md[64];
    __shared__ double Td[64];
    const int t = threadIdx.x;

    if (t < NF) {
        double r   = 0.999 / (1.0 + exp(-(double)lr[t]));
        double ang = 3.14159265358979323846 / (1.0 + exp(-(double)ra[t]));
        ws[COEF_OFF + t * 5 + 0] = b0[t];
        ws[COEF_OFF + t * 5 + 1] = b1[t];
        ws[COEF_OFF + t * 5 + 2] = b2[t];
        ws[COEF_OFF + t * 5 + 3] = (float)(-2.0 * r * cos(ang));
        ws[COEF_OFF + t * 5 + 4] = (float)(r * r);
    }
    __syncthreads();

    if (t < 8) {
        double cb0[NF], cb1[NF], cb2[NF], ca1[NF], ca2[NF];
        for (int f = 0; f < NF; ++f) {
            cb0[f] = (double)ws[COEF_OFF + f * 5 + 0];
            cb1[f] = (double)ws[COEF_OFF + f * 5 + 1];
            cb2[f] = (double)ws[COEF_OFF + f * 5 + 2];
            ca1[f] = (double)ws[COEF_OFF + f * 5 + 3];
            ca2[f] = (double)ws[COEF_OFF + f * 5 + 4];
        }
        double s[8];
        for (int r = 0; r < 8; ++r) s[r] = 0.0;
        s[t] = 1.0;  // unit initial state e_t
        for (int n = 0; n < CHUNK; ++n) {
            double v = 0.0;  // zero input
            for (int f = 0; f < NF; ++f) {
                double y    = cb0[f] * v + s[2 * f];
                s[2 * f]     = cb1[f] * v - ca1[f] * y + s[2 * f + 1];
                s[2 * f + 1] = cb2[f] * v - ca2[f] * y;
                v = y;
            }
        }
        for (int r = 0; r < 8; ++r) Md[r * 8 + t] = s[r];  // column t of M
    }
    __syncthreads();

    if (t < 64) ws[M_OFF + t] = (float)Md[t];

    // M16 = M^16: square 4 times
    for (int sq = 0; sq < 4; ++sq) {
        if (t < 64) {
            int r = t >> 3, c = t & 7;
            double acc = 0.0;
            for (int m = 0; m < 8; ++m) acc += Md[r * 8 + m] * Md[m * 8 + c];
            Td[t] = acc;
        }
        __syncthreads();
        if (t < 64) Md[t] = Td[t];
        __syncthreads();
    }
    if (t < 64) ws[M16_OFF + t] = (float)Md[t];
}

// ---------------------------------------------------------------------------
// Kernels 1 & 3: per-(batch,block) cascade simulation.
//   WRITE=0: start from zero state, emit final state d[b,k].
//   WRITE=1: start from s_in[b,k], emit y.
// ---------------------------------------------------------------------------
template <int WRITE>
__global__ __launch_bounds__(256) void phase13_k(const float* __restrict__ x,
                                                 float* __restrict__ ws,
                                                 float* __restrict__ y) {
    const int tid = blockIdx.x * blockDim.x + threadIdx.x;
    if (tid >= Bn * NBLK) return;
    const int b = tid / NBLK;
    const int k = tid % NBLK;

    float c0[NF], c1[NF], c2[NF], A1[NF], A2[NF];
#pragma unroll
    for (int f = 0; f < NF; ++f) {
        c0[f] = ws[COEF_OFF + f * 5 + 0];
        c1[f] = ws[COEF_OFF + f * 5 + 1];
        c2[f] = ws[COEF_OFF + f * 5 + 2];
        A1[f] = ws[COEF_OFF + f * 5 + 3];
        A2[f] = ws[COEF_OFF + f * 5 + 4];
    }

    float s[8];
    if (WRITE) {
        const float* si = ws + S_OFF + (size_t)tid * 8;
#pragma unroll
        for (int r = 0; r < 8; ++r) s[r] = si[r];
    } else {
#pragma unroll
        for (int r = 0; r < 8; ++r) s[r] = 0.f;
    }

    const float4* xc = (const float4*)(x + (size_t)b * Ln + (size_t)k * CHUNK);
    float4* yc = (float4*)(y + (size_t)b * Ln + (size_t)k * CHUNK);

#pragma unroll 4
    for (int i = 0; i < CHUNK / 4; ++i) {
        float4 v = xc[i];
        float vv[4] = {v.x, v.y, v.z, v.w};
#pragma unroll
        for (int e = 0; e < 4; ++e) {
            float u = vv[e];
#pragma unroll
            for (int f = 0; f < NF; ++f) {
                float yv     = fmaf(c0[f], u, s[2 * f]);
                s[2 * f]     = fmaf(-A1[f], yv, fmaf(c1[f], u, s[2 * f + 1]));
                s[2 * f + 1] = fmaf(-A2[f], yv, c2[f] * u);
                u = yv;
            }
            vv[e] = u;
        }
        if (WRITE) {
            float4 o;
            o.x = vv[0]; o.y = vv[1]; o.z = vv[2]; o.w = vv[3];
            yc[i] = o;
        }
    }

    if (!WRITE) {
        float* d = ws + D_OFF + (size_t)tid * 8;
#pragma unroll
        for (int r = 0; r < 8; ++r) d[r] = s[r];
    }
}

// ---------------------------------------------------------------------------
// Kernel 2: per-batch affine scan  s_in[k+1] = M*s_in[k] + d[k].
// One workgroup (1 wave) per batch row; two-level scan:
//   A: each lane locally scans its 16 consecutive blocks from zero state
//   B: masked 63-step scan over lane endpoints with M16 = M^16
//   C: lanes re-scan their 16 blocks from the stitched entry state, writing s_in
// ---------------------------------------------------------------------------
__global__ __launch_bounds__(64) void phase2_k(float* __restrict__ ws) {
    const int b    = blockIdx.x;
    const int lane = threadIdx.x;

    float M[64], M16[64];
#pragma unroll
    for (int i = 0; i < 64; ++i) {
        M[i]   = ws[M_OFF + i];
        M16[i] = ws[M16_OFF + i];
    }

    const float* d  = ws + D_OFF + (size_t)b * NBLK * 8;
    float*       so = ws + S_OFF + (size_t)b * NBLK * 8;

    __shared__ float eL[P2LANES][8];

    // level A: local zero-state scan
    float s[8];
#pragma unroll
    for (int r = 0; r < 8; ++r) s[r] = 0.f;
    for (int i = 0; i < BPL; ++i) {
        const float* dk = d + (size_t)(lane * BPL + i) * 8;
        float t[8];
#pragma unroll
        for (int r = 0; r < 8; ++r) {
            float acc = dk[r];
#pragma unroll
            for (int c = 0; c < 8; ++c) acc = fmaf(M[r * 8 + c], s[c], acc);
            t[r] = acc;
        }
#pragma unroll
        for (int r = 0; r < 8; ++r) s[r] = t[r];
    }
#pragma unroll
    for (int r = 0; r < 8; ++r) eL[lane][r] = s[r];
    __syncthreads();

    // level B: entry state for this lane's super-block
    float sb[8];
#pragma unroll
    for (int r = 0; r < 8; ++r) sb[r] = 0.f;
    for (int i = 0; i < P2LANES - 1; ++i) {
        float t[8];
#pragma unroll
        for (int r = 0; r < 8; ++r) {
            float acc = eL[i][r];
#pragma unroll
            for (int c = 0; c < 8; ++c) acc = fmaf(M16[r * 8 + c], sb[c], acc);
            t[r] = acc;
        }
        const bool take = (i < lane);
#pragma unroll
        for (int r = 0; r < 8; ++r) sb[r] = take ? t[r] : sb[r];
    }

    // level C: re-scan writing block entry states
    for (int i = 0; i < BPL; ++i) {
        const size_t k = (size_t)(lane * BPL + i);
#pragma unroll
        for (int r = 0; r < 8; ++r) so[k * 8 + r] = sb[r];
        const float* dk = d + k * 8;
        float t[8];
#pragma unroll
        for (int r = 0; r < 8; ++r) {
            float acc = dk[r];
#pragma unroll
            for (int c = 0; c < 8; ++c) acc = fmaf(M[r * 8 + c], sb[c], acc);
            t[r] = acc;
        }
#pragma unroll
        for (int r = 0; r < 8; ++r) sb[r] = t[r];
    }
}

// ---------------------------------------------------------------------------
extern "C" void kernel_launch(void* const* d_in, const int* in_sizes, int n_in,
                              void* d_out, int out_size, void* d_ws, size_t ws_size,
                              hipStream_t stream) {
    const float* x  = (const float*)d_in[0];
    const float* lr = (const float*)d_in[1];
    const float* ra = (const float*)d_in[2];
    const float* b0 = (const float*)d_in[3];
    const float* b1 = (const float*)d_in[4];
    const float* b2 = (const float*)d_in[5];
    float* y  = (float*)d_out;
    float* ws = (float*)d_ws;

    precompute_k<<<dim3(1), dim3(64), 0, stream>>>(lr, ra, b0, b1, b2, ws);

    const int total = Bn * NBLK;  // 32768 threads
    phase13_k<0><<<dim3(total / 256), dim3(256), 0, stream>>>(x, ws, y);
    phase2_k<<<dim3(Bn), dim3(P2LANES), 0, stream>>>(ws);
    phase13_k<1><<<dim3(total / 256), dim3(256), 0, stream>>>(x, ws, y);
}

// Round 2
// 117.933 us; speedup vs baseline: 1.0420x; 1.0420x over previous
//
#include <hip/hip_runtime.h>
#include <math.h>

#define Bn 32
#define Ln 524288
#define NF 4

// ws layout in floats
#define COEF_OFF 0      // 20 floats: per filter b0,b1,b2,a1,a2
#define M64_OFF  64     // A^64
#define M512_OFF 128    // A^512
#define KS_OFF   192    // 9 matrices: (A^1024)^(2^j), j=0..8  (576 floats)
#define DBUF_OFF 832    // in-place block-state buffer: Bn*NBLK*8 floats

// ---------------------------------------------------------------------------
// Kernel 0: coefficients (double, rounded to f32 so dynamics match phase13),
// M = A^64 via unit-state simulation with the f32-rounded coefs (double
// accumulation), then a squaring chain producing A^512 and (A^1024)^(2^j).
// One block, 64 threads.
// ---------------------------------------------------------------------------
__global__ void precompute_k(const float* __restrict__ lr,
                             const float* __restrict__ ra,
                             const float* __restrict__ b0,
                             const float* __restrict__ b1,
                             const float* __restrict__ b2,
                             float* __restrict__ ws) {
    __shared__ double Md[64];
    __shared__ double Td[64];
    const int t = threadIdx.x;

    if (t < NF) {
        double r   = 0.999 / (1.0 + exp(-(double)lr[t]));
        double ang = 3.14159265358979323846 / (1.0 + exp(-(double)ra[t]));
        ws[COEF_OFF + t * 5 + 0] = b0[t];
        ws[COEF_OFF + t * 5 + 1] = b1[t];
        ws[COEF_OFF + t * 5 + 2] = b2[t];
        ws[COEF_OFF + t * 5 + 3] = (float)(-2.0 * r * cos(ang));
        ws[COEF_OFF + t * 5 + 4] = (float)(r * r);
    }
    __syncthreads();

    if (t < 8) {
        double cb0[NF], cb1[NF], cb2[NF], ca1[NF], ca2[NF];
        for (int f = 0; f < NF; ++f) {
            cb0[f] = (double)ws[COEF_OFF + f * 5 + 0];
            cb1[f] = (double)ws[COEF_OFF + f * 5 + 1];
            cb2[f] = (double)ws[COEF_OFF + f * 5 + 2];
            ca1[f] = (double)ws[COEF_OFF + f * 5 + 3];
            ca2[f] = (double)ws[COEF_OFF + f * 5 + 4];
        }
        double s[8];
        for (int r = 0; r < 8; ++r) s[r] = 0.0;
        s[t] = 1.0;  // unit initial state e_t
        for (int n = 0; n < 64; ++n) {
            double v = 0.0;  // zero input
            for (int f = 0; f < NF; ++f) {
                double y     = cb0[f] * v + s[2 * f];
                s[2 * f]     = cb1[f] * v - ca1[f] * y + s[2 * f + 1];
                s[2 * f + 1] = cb2[f] * v - ca2[f] * y;
                v = y;
            }
        }
        for (int r = 0; r < 8; ++r) Md[r * 8 + t] = s[r];  // column t of A^64
    }
    __syncthreads();

    ws[M64_OFF + t] = (float)Md[t];

    // squaring chain: A^64 -> 128 -> 256 -> 512 -> 1024 -> ... -> 262144
    for (int sq = 0; sq < 12; ++sq) {
        const int r = t >> 3, c = t & 7;
        double acc = 0.0;
        for (int m = 0; m < 8; ++m) acc += Md[r * 8 + m] * Md[m * 8 + c];
        Td[t] = acc;
        __syncthreads();
        Md[t] = Td[t];
        __syncthreads();
        if (sq == 2) ws[M512_OFF + t] = (float)Md[t];              // A^512
        if (sq >= 3) ws[KS_OFF + (sq - 3) * 64 + t] = (float)Md[t]; // A^(1024*2^(sq-3))
    }
}

// ---------------------------------------------------------------------------
// Kernels 1 & 3: per-(batch,block) cascade simulation over CHUNK samples.
//   WRITE=0: start from zero state, emit final state into dbuf[b,k].
//   WRITE=1: start from dbuf[b,k] (entry state after phase2), emit y.
// ---------------------------------------------------------------------------
template <int CHUNK, int WRITE>
__global__ __launch_bounds__(256, 4) void phase13_k(const float* __restrict__ x,
                                                    float* __restrict__ ws,
                                                    float* __restrict__ y) {
    constexpr int NBLK = Ln / CHUNK;
    const int tid = blockIdx.x * 256 + threadIdx.x;
    if (tid >= Bn * NBLK) return;
    const int b = tid / NBLK;  // NBLK pow2 -> shift
    const int k = tid % NBLK;

    float c0[NF], c1[NF], c2[NF], A1[NF], A2[NF];
#pragma unroll
    for (int f = 0; f < NF; ++f) {
        c0[f] = ws[COEF_OFF + f * 5 + 0];
        c1[f] = ws[COEF_OFF + f * 5 + 1];
        c2[f] = ws[COEF_OFF + f * 5 + 2];
        A1[f] = ws[COEF_OFF + f * 5 + 3];
        A2[f] = ws[COEF_OFF + f * 5 + 4];
    }

    float* dslot = ws + DBUF_OFF + (size_t)tid * 8;
    float s[8];
    if (WRITE) {
#pragma unroll
        for (int r = 0; r < 8; ++r) s[r] = dslot[r];
    } else {
#pragma unroll
        for (int r = 0; r < 8; ++r) s[r] = 0.f;
    }

    const float4* xc = (const float4*)(x + (size_t)b * Ln + (size_t)k * CHUNK);
    float4* yc = (float4*)(y + (size_t)b * Ln + (size_t)k * CHUNK);

#pragma unroll 4
    for (int i = 0; i < CHUNK / 4; ++i) {
        float4 v = xc[i];
        float vv[4] = {v.x, v.y, v.z, v.w};
#pragma unroll
        for (int e = 0; e < 4; ++e) {
            float u = vv[e];
#pragma unroll
            for (int f = 0; f < NF; ++f) {
                float yv     = fmaf(c0[f], u, s[2 * f]);
                s[2 * f]     = fmaf(-A1[f], yv, fmaf(c1[f], u, s[2 * f + 1]));
                s[2 * f + 1] = fmaf(-A2[f], yv, c2[f] * u);
                u = yv;
            }
            vv[e] = u;
        }
        if (WRITE) {
            float4 o;
            o.x = vv[0]; o.y = vv[1]; o.z = vv[2]; o.w = vv[3];
            yc[i] = o;
        }
    }

    if (!WRITE) {
#pragma unroll
        for (int r = 0; r < 8; ++r) dslot[r] = s[r];
    }
}

// ---------------------------------------------------------------------------
// Kernel 2: per-batch affine scan  s_{k+1} = M1*s_k + d_k  over NBLK blocks,
// in-place in dbuf (d_k replaced by entry state s_k).
// One workgroup (512 threads) per batch row:
//   A: thread scans its BPT consecutive blocks from zero -> span endpoint e_t
//   B: Kogge-Stone inclusive scan over 512 spans in LDS with T^(2^j),
//      T = M1^BPT = A^1024 (same for both CHUNK configs)
//   C: thread re-scans its span from entry g_{t-1}, overwriting d_k with s_k
// ---------------------------------------------------------------------------
template <int CHUNK>
__global__ __launch_bounds__(512) void phase2_k(float* __restrict__ ws) {
    constexpr int NBLK = Ln / CHUNK;
    constexpr int BPT  = NBLK / 512;
    const int b = blockIdx.x;
    const int t = threadIdx.x;

    float* rowd = ws + DBUF_OFF + (size_t)b * NBLK * 8;

    float M1[64];
    const int moff = (CHUNK == 64) ? M64_OFF : M512_OFF;
#pragma unroll
    for (int i = 0; i < 64; ++i) M1[i] = ws[moff + i];

    // level A: zero-entry scan of own span
    float g[8];
#pragma unroll
    for (int r = 0; r < 8; ++r) g[r] = 0.f;
    for (int i = 0; i < BPT; ++i) {
        const float* dk = rowd + (size_t)(t * BPT + i) * 8;
        float nt[8];
#pragma unroll
        for (int r = 0; r < 8; ++r) {
            float acc = dk[r];
#pragma unroll
            for (int c = 0; c < 8; ++c) acc = fmaf(M1[r * 8 + c], g[c], acc);
            nt[r] = acc;
        }
#pragma unroll
        for (int r = 0; r < 8; ++r) g[r] = nt[r];
    }

    // level B: Kogge-Stone over 512 spans (9 rounds), LDS padded stride 9
    __shared__ float gl[512][9];
#pragma unroll
    for (int r = 0; r < 8; ++r) gl[t][r] = g[r];
    __syncthreads();

    for (int j = 0; j < 9; ++j) {
        const int dlt = 1 << j;
        float part[8];
        if (t >= dlt) {
#pragma unroll
            for (int r = 0; r < 8; ++r) part[r] = gl[t - dlt][r];
        }
        __syncthreads();
        if (t >= dlt) {
            const float* Tj = ws + KS_OFF + j * 64;
#pragma unroll
            for (int r = 0; r < 8; ++r) {
                float acc = g[r];
#pragma unroll
                for (int c = 0; c < 8; ++c) acc = fmaf(Tj[r * 8 + c], part[c], acc);
                g[r] = acc;
            }
        }
#pragma unroll
        for (int r = 0; r < 8; ++r) gl[t][r] = g[r];
        __syncthreads();
    }

    // entry state of my span = inclusive value of span t-1 (0 for t==0)
    float cur[8];
    if (t > 0) {
#pragma unroll
        for (int r = 0; r < 8; ++r) cur[r] = gl[t - 1][r];
    } else {
#pragma unroll
        for (int r = 0; r < 8; ++r) cur[r] = 0.f;
    }

    // level C: re-scan span, overwriting d_k with entry state s_k
    for (int i = 0; i < BPT; ++i) {
        float* dk = rowd + (size_t)(t * BPT + i) * 8;
        float tmp[8];
#pragma unroll
        for (int r = 0; r < 8; ++r) tmp[r] = dk[r];
#pragma unroll
        for (int r = 0; r < 8; ++r) dk[r] = cur[r];
        float nt[8];
#pragma unroll
        for (int r = 0; r < 8; ++r) {
            float acc = tmp[r];
#pragma unroll
            for (int c = 0; c < 8; ++c) acc = fmaf(M1[r * 8 + c], cur[c], acc);
            nt[r] = acc;
        }
#pragma unroll
        for (int r = 0; r < 8; ++r) cur[r] = nt[r];
    }
}

// ---------------------------------------------------------------------------
extern "C" void kernel_launch(void* const* d_in, const int* in_sizes, int n_in,
                              void* d_out, int out_size, void* d_ws, size_t ws_size,
                              hipStream_t stream) {
    const float* x  = (const float*)d_in[0];
    const float* lr = (const float*)d_in[1];
    const float* ra = (const float*)d_in[2];
    const float* b0 = (const float*)d_in[3];
    const float* b1 = (const float*)d_in[4];
    const float* b2 = (const float*)d_in[5];
    float* y  = (float*)d_out;
    float* ws = (float*)d_ws;

    precompute_k<<<dim3(1), dim3(64), 0, stream>>>(lr, ra, b0, b1, b2, ws);

    const size_t need64 = (DBUF_OFF + (size_t)Bn * (Ln / 64) * 8) * sizeof(float);
    if (ws_size >= need64) {
        constexpr int C = 64;
        const int total = Bn * (Ln / C);  // 262144 threads
        phase13_k<C, 0><<<dim3(total / 256), dim3(256), 0, stream>>>(x, ws, y);
        phase2_k<C><<<dim3(Bn), dim3(512), 0, stream>>>(ws);
        phase13_k<C, 1><<<dim3(total / 256), dim3(256), 0, stream>>>(x, ws, y);
    } else {
        constexpr int C = 512;
        const int total = Bn * (Ln / C);  // 32768 threads
        phase13_k<C, 0><<<dim3(total / 256), dim3(256), 0, stream>>>(x, ws, y);
        phase2_k<C><<<dim3(Bn), dim3(512), 0, stream>>>(ws);
        phase13_k<C, 1><<<dim3(total / 256), dim3(256), 0, stream>>>(x, ws, y);
    }
}